// Round 11
// baseline (261.206 us; speedup 1.0000x reference)
//
#include <hip/hip_runtime.h>
#include <math.h>

#define Bx 16
#define Cx 64
#define Hx 128
#define Wx 128
#define HWx (Hx * Wx)

#define TW 32
#define TH 8
#define CCH 8
#define HALO_W (TW + 2)
#define HALO_H (TH + 2)
#define CPLANE (HALO_H * HALO_W)          // 340
#define CHUNK_ELEMS (CCH * CPLANE)        // 2720
#define NCHUNK (Cx / CCH)                 // 8

// workspace layout (float offsets)
#define WS_CWT   0                         // cwT[c*64+o]            4096
#define WS_GPACK 4096                      // gpack12[c*96+rg*12+k]  6144  (rg=r*2+g)
#define WS_KERN  10240                     // per-b [c*36+k*4+g]     16*2304
#define WS_ATT   47104                     // per-b [c*4+r]          16*256

// ---------------- prep: hypernetwork + weight repacking (unchanged, passing) ----------------
__global__ __launch_bounds__(256)
void da_prep(const float* __restrict__ x_deg,
             const float* __restrict__ kw1,
             const float* __restrict__ kw2,
             const float* __restrict__ convw,
             const float* __restrict__ ca_w1,
             const float* __restrict__ ca_w2,
             const float* __restrict__ g1w,
             const float* __restrict__ g2w,
             float* __restrict__ ws)
{
    const int b = blockIdx.x;
    const int tid = threadIdx.x;

    if (b == Bx) {
        for (int i = tid; i < 4096; i += 256) {           // cwT[c*64+o] = convw[o*64+c]
            const int o = i >> 6, c = i & 63;
            ws[WS_CWT + c * 64 + o] = convw[o * 64 + c];
        }
        for (int i = tid; i < 6144; i += 256) {           // gpack12[c][rg=r*2+g][12]
            const int c = i / 96;
            int rem = i - c * 96;
            const int rg = rem / 12;
            const int k  = rem - rg * 12;
            const int r = rg >> 1;
            const int g = rg & 1;
            const float* src = g ? g2w : g1w;
            ws[WS_GPACK + i] = (k < 9) ? src[(r * Cx + c) * 9 + k] : 0.f;
        }
        return;
    }

    __shared__ float h1[16];
    __shared__ float a1[16];
    if (tid < 32) {
        const int j = tid & 15;
        const float* wsrc = (tid < 16) ? (kw1 + j * Cx) : (ca_w1 + j * Cx);
        float acc = 0.f;
        #pragma unroll 8
        for (int c = 0; c < Cx; ++c) acc = fmaf(x_deg[b * Cx + c], wsrc[c], acc);
        acc = acc > 0.f ? acc : 0.1f * acc;               // leaky_relu 0.1
        if (tid < 16) h1[j] = acc; else a1[j] = acc;
    }
    __syncthreads();

    for (int o4 = tid; o4 < 4 * 576; o4 += 256) {
        const int g = o4 / 576;
        const int o = o4 - g * 576;
        float acc = 0.f;
        #pragma unroll
        for (int i = 0; i < 4; ++i)
            acc = fmaf(h1[g * 4 + i], kw2[(g * 576 + o) * 4 + i], acc);
        const int c = o / 9;
        const int k = o - c * 9;
        ws[WS_KERN + b * 2304 + c * 36 + k * 4 + g] = acc;
    }
    {
        const int r = tid >> 6;
        const int c = tid & 63;
        float acc = 0.f;
        #pragma unroll
        for (int i = 0; i < 4; ++i)
            acc = fmaf(a1[r * 4 + i], ca_w2[(r * Cx + c) * 4 + i], acc);
        ws[WS_ATT + b * 256 + c * 4 + r] = 1.f / (1.f + expf(-acc));
    }
}

// ---------------- main fused kernel: R10 + wave-uniform weights via SMEM path ----------------
// R10 diagnosis: LDS pipe saturated (~4600 LDS instrs/wave, 55% = weight
// b128 broadcasts). Weights are wave-uniform and 16B-aligned-packed ->
// read from GLOBAL with uniform indices: compiler emits batched
// s_load_dwordx16 into SGPRs (separate SMEM pipe; v_fma takes one SGPR
// operand; zero VGPR/LDS cost). Everything else identical to R10:
// batched phase staging, no cross-phase pipelining (spill law, R2-R8),
// y[] statically indexed, bit-identical FMA chains for argmax safety.
__global__ __launch_bounds__(256, 2)
void da_main(const float* __restrict__ x0,
             const float* __restrict__ ws,
             const float* __restrict__ g1b,
             const float* __restrict__ g2b,
             const float* __restrict__ convb,
             float* __restrict__ out)
{
    const int b  = blockIdx.z;
    const int h0 = blockIdx.y * TH;
    const int w0 = blockIdx.x * TW;
    const int tid = threadIdx.x;
    const int tx = tid & (TW - 1);
    const int ty = tid >> 5;

    // LDS: only per-lane-divergent data (skern r1-indexed, satt r2-indexed)
    __shared__ __align__(16) float swts[2560];        // [0,2304)=skern [c][k][r]; [2304,2560)=satt [c][r]
    __shared__ __align__(16) float sx[CHUNK_ELEMS];   // 10.6 KB x chunk (halo)
    // total ~21 KB LDS

    const float* xb  = x0 + (size_t)b * Cx * HWx;
    const float* kws = ws + WS_KERN + b * 2304;
    const float* aws = ws + WS_ATT  + b * 256;
    const float* gpk = ws + WS_GPACK;                 // uniform-read -> SMEM path
    const float* cwt = ws + WS_CWT;                   // uniform-read -> SMEM path

    // --- per-thread staging offsets, computed ONCE (named ints, no array) ---
    int o0, o1, o2, o3, o4, o5, o6, o7, o8, o9, o10;
    unsigned vmask = 0u;
#define MKOFF(i, oname)                                                        \
    do {                                                                       \
        const int e   = tid + (i) * 256;                                       \
        const int cc  = e / CPLANE;                                            \
        const int rem = e - cc * CPLANE;                                       \
        const int row = rem / HALO_W;                                          \
        const int col = rem - row * HALO_W;                                    \
        const int gh  = h0 - 1 + row;                                          \
        const int gw  = w0 - 1 + col;                                          \
        oname = cc * HWx + gh * Wx + gw;                                       \
        if (e < CHUNK_ELEMS && (unsigned)gh < Hx && (unsigned)gw < Wx)         \
            vmask |= (1u << (i));                                              \
    } while (0)
    MKOFF(0, o0);  MKOFF(1, o1);  MKOFF(2, o2);  MKOFF(3, o3);
    MKOFF(4, o4);  MKOFF(5, o5);  MKOFF(6, o6);  MKOFF(7, o7);
    MKOFF(8, o8);  MKOFF(9, o9);  MKOFF(10, o10);
#undef MKOFF

    // batched staging of one chunk: issue all loads, then all LDS writes
#define STAGE_CHUNK(ch)                                                        \
    do {                                                                       \
        const float* src = xb + (size_t)(ch) * CCH * HWx;                      \
        float v0 = 0.f, v1 = 0.f, v2 = 0.f, v3 = 0.f, v4 = 0.f, v5 = 0.f;     \
        float v6 = 0.f, v7 = 0.f, v8 = 0.f, v9 = 0.f, v10 = 0.f;              \
        if (vmask & 1u)      v0  = src[o0];                                    \
        if (vmask & 2u)      v1  = src[o1];                                    \
        if (vmask & 4u)      v2  = src[o2];                                    \
        if (vmask & 8u)      v3  = src[o3];                                    \
        if (vmask & 16u)     v4  = src[o4];                                    \
        if (vmask & 32u)     v5  = src[o5];                                    \
        if (vmask & 64u)     v6  = src[o6];                                    \
        if (vmask & 128u)    v7  = src[o7];                                    \
        if (vmask & 256u)    v8  = src[o8];                                    \
        if (vmask & 512u)    v9  = src[o9];                                    \
        if (vmask & 1024u)   v10 = src[o10];                                   \
        sx[tid]           = v0;   sx[tid + 256]  = v1;                         \
        sx[tid + 512]     = v2;   sx[tid + 768]  = v3;                         \
        sx[tid + 1024]    = v4;   sx[tid + 1280] = v5;                         \
        sx[tid + 1536]    = v6;   sx[tid + 1792] = v7;                         \
        sx[tid + 2048]    = v8;   sx[tid + 2304] = v9;                         \
        if (tid < CHUNK_ELEMS - 2560) sx[tid + 2560] = v10;                    \
    } while (0)

    // ================= PASS 1: guide convs -> argmax =================
    float ga[8];
    #pragma unroll
    for (int r = 0; r < 4; ++r) { ga[r] = g1b[r]; ga[4 + r] = g2b[r]; }

    #pragma unroll 1
    for (int ch = 0; ch < NCHUNK; ++ch) {
        __syncthreads();
        STAGE_CHUNK(ch);
        __syncthreads();

        float pg[8] = {0.f, 0.f, 0.f, 0.f, 0.f, 0.f, 0.f, 0.f};
        #pragma unroll
        for (int cc = 0; cc < CCH; ++cc) {
            const int c = ch * CCH + cc;
            float n[9];
            #pragma unroll
            for (int kh = 0; kh < 3; ++kh)
                #pragma unroll
                for (int kw = 0; kw < 3; ++kw)
                    n[kh * 3 + kw] = sx[cc * CPLANE + (ty + kh) * HALO_W + (tx + kw)];
            const float4* gpv = (const float4*)(gpk + c * 96);   // UNIFORM -> s_load
            #pragma unroll
            for (int rg = 0; rg < 8; ++rg) {          // rg = r*2+g
                const float4 q0 = gpv[rg * 3 + 0];
                const float4 q1 = gpv[rg * 3 + 1];
                const float4 q2 = gpv[rg * 3 + 2];
                float s = 0.f;                        // k-ascending, bit-identical chain
                s = fmaf(n[0], q0.x, s); s = fmaf(n[1], q0.y, s); s = fmaf(n[2], q0.z, s);
                s = fmaf(n[3], q0.w, s); s = fmaf(n[4], q1.x, s); s = fmaf(n[5], q1.y, s);
                s = fmaf(n[6], q1.z, s); s = fmaf(n[7], q1.w, s); s = fmaf(n[8], q2.x, s);
                pg[(rg >> 1) + (rg & 1) * 4] += s;    // static index (unrolled rg)
            }
        }
        #pragma unroll
        for (int i = 0; i < 8; ++i) ga[i] += pg[i];
    }

    int r1 = 0, r2 = 0;
    {
        float m = ga[0];
        #pragma unroll
        for (int r = 1; r < 4; ++r) if (ga[r] > m) { m = ga[r]; r1 = r; }   // first-max ties
        float m2 = ga[4];
        #pragma unroll
        for (int r = 1; r < 4; ++r) if (ga[4 + r] > m2) { m2 = ga[4 + r]; r2 = r; }
    }

    // --- pass transition: stage skern+satt into LDS (batched; lane-divergent reads later) ---
    __syncthreads();
    {
        const float4* k4 = (const float4*)kws;
        const float4 k0 = k4[tid], k1 = k4[tid + 256];
        const float kt = kws[2048 + tid];
        const float at = aws[tid];
        float4* kd4 = (float4*)swts;                  // skern at 0
        kd4[tid] = k0; kd4[tid + 256] = k1;
        swts[2048 + tid] = kt;                        // skern tail
        swts[2304 + tid] = at;                        // satt
    }
    // visibility: pass-2 loop-top barrier

    // ================= PASS 2: routed depthwise + 1x1 =================
    float y[Cx];
    #pragma unroll
    for (int o = 0; o < Cx; ++o) y[o] = 0.f;

    #pragma unroll 1
    for (int ch = 0; ch < NCHUNK; ++ch) {
        __syncthreads();
        STAGE_CHUNK(ch);
        __syncthreads();

        #pragma unroll
        for (int cc = 0; cc < CCH; ++cc) {
            const int c = ch * CCH + cc;
            float n[9];
            #pragma unroll
            for (int kh = 0; kh < 3; ++kh)
                #pragma unroll
                for (int kw = 0; kw < 3; ++kw)
                    n[kh * 3 + kw] = sx[cc * CPLANE + (ty + kh) * HALO_W + (tx + kw)];

            float dw = 0.f;
            #pragma unroll
            for (int k = 0; k < 9; ++k)
                dw = fmaf(n[k], swts[c * 36 + k * 4 + r1], dw);
            const float routed = dw > 0.f ? dw : 0.1f * dw;

            const float4* cwv = (const float4*)(cwt + c * 64);   // UNIFORM -> s_load
            #pragma unroll
            for (int q = 0; q < 16; ++q) {            // y statically indexed only
                const float4 w4 = cwv[q];
                y[q * 4 + 0] = fmaf(w4.x, routed, y[q * 4 + 0]);
                y[q * 4 + 1] = fmaf(w4.y, routed, y[q * 4 + 1]);
                y[q * 4 + 2] = fmaf(w4.z, routed, y[q * 4 + 2]);
                y[q * 4 + 3] = fmaf(w4.w, routed, y[q * 4 + 3]);
            }
        }
    }

    // --- epilogue: bias + CA branch (x center re-read) + store ---
    const int hh = h0 + ty;
    const int ww = w0 + tx;
    float* op = out + (size_t)b * Cx * HWx + hh * Wx + ww;
    const float* xp = xb + hh * Wx + ww;
    #pragma unroll
    for (int o = 0; o < Cx; ++o) {
        const float v = y[o] + convb[o] + xp[(size_t)o * HWx] * swts[2304 + o * 4 + r2];
        op[(size_t)o * HWx] = v;
    }
}

extern "C" void kernel_launch(void* const* d_in, const int* in_sizes, int n_in,
                              void* d_out, int out_size, void* d_ws, size_t ws_size,
                              hipStream_t stream) {
    const float* x0     = (const float*)d_in[0];
    const float* x_deg  = (const float*)d_in[1];
    const float* kw1    = (const float*)d_in[2];
    const float* kw2    = (const float*)d_in[3];
    const float* convw  = (const float*)d_in[4];
    const float* convb  = (const float*)d_in[5];
    const float* ca_w1  = (const float*)d_in[6];
    const float* ca_w2  = (const float*)d_in[7];
    const float* g1w    = (const float*)d_in[8];
    const float* g1b    = (const float*)d_in[9];
    const float* g2w    = (const float*)d_in[10];
    const float* g2b    = (const float*)d_in[11];
    float* outp = (float*)d_out;
    float* wsf  = (float*)d_ws;

    da_prep<<<Bx + 1, 256, 0, stream>>>(x_deg, kw1, kw2, convw, ca_w1, ca_w2,
                                        g1w, g2w, wsf);

    dim3 grid(Wx / TW, Hx / TH, Bx);   // 4 x 16 x 16 = 1024 blocks
    da_main<<<grid, 256, 0, stream>>>(x0, wsf, g1b, g2b, convb, outp);
}

// Round 12
// 146.036 us; speedup vs baseline: 1.7886x; 1.7886x over previous
//
#include <hip/hip_runtime.h>
#include <math.h>

#define Bx 16
#define Cx 64
#define Hx 128
#define Wx 128
#define HWx (Hx * Wx)

#define TW 32
#define TH 8
#define CCH 8
#define HALO_W (TW + 2)
#define HALO_H (TH + 2)
#define CPLANE (HALO_H * HALO_W)          // 340
#define CHUNK_ELEMS (CCH * CPLANE)        // 2720
#define NCHUNK (Cx / CCH)                 // 8

// workspace layout (float/u32 offsets)
#define WS_CWB   0                         // 1x1 B-fragments bf16: 8 tiles*64 lanes*4 u32 = 2048
#define WS_GPACK 2048                      // gpack12[c*96+rg*12+k]  6144  (rg=r*2+g)
#define WS_KERN  8192                      // per-b [c*36+k*4+g]     16*2304 = 36864
#define WS_ATT   45056                     // per-b [c*4+r]          16*256  = 4096
// total 49152 floats = 192 KB

typedef short bf16x8 __attribute__((ext_vector_type(8)));
typedef float f32x4  __attribute__((ext_vector_type(4)));
typedef unsigned int u32x4 __attribute__((ext_vector_type(4)));

__device__ __host__ inline unsigned rne_bf16(float f) {
    union { float f; unsigned u; } v; v.f = f;
    return (v.u + 0x7fffu + ((v.u >> 16) & 1u)) >> 16;
}

// ---------------- prep: hypernetwork + weight repacking ----------------
__global__ __launch_bounds__(256)
void da_prep(const float* __restrict__ x_deg,
             const float* __restrict__ kw1,
             const float* __restrict__ kw2,
             const float* __restrict__ convw,
             const float* __restrict__ ca_w1,
             const float* __restrict__ ca_w2,
             const float* __restrict__ g1w,
             const float* __restrict__ g2w,
             float* __restrict__ ws)
{
    const int b = blockIdx.x;
    const int tid = threadIdx.x;
    unsigned int* wsu = (unsigned int*)ws;

    if (b == Bx) {
        // 1x1 weights as MFMA B-fragments, bf16 RNE.
        // B[k=c][col=o]; lane holds k=(lane>>4)*8+j, col=lane&15; tile t=nt*2+ks.
        for (int i = tid; i < 2048; i += 256) {
            const int t    = i >> 8;
            const int rem  = i & 255;
            const int lane = rem >> 2;
            const int w    = rem & 3;
            const int nt = t >> 1, ks = t & 1;
            const int o = nt * 16 + (lane & 15);
            const int c = ks * 32 + ((lane >> 4) << 3) + w * 2;
            const unsigned lo = rne_bf16(convw[o * 64 + c]);
            const unsigned hi = rne_bf16(convw[o * 64 + c + 1]);
            wsu[WS_CWB + i] = lo | (hi << 16);
        }
        for (int i = tid; i < 6144; i += 256) {           // gpack12[c][rg=r*2+g][12]
            const int c = i / 96;
            int rem = i - c * 96;
            const int rg = rem / 12;
            const int k  = rem - rg * 12;
            const int r = rg >> 1;
            const int g = rg & 1;
            const float* src = g ? g2w : g1w;
            ws[WS_GPACK + i] = (k < 9) ? src[(r * Cx + c) * 9 + k] : 0.f;
        }
        return;
    }

    __shared__ float h1[16];
    __shared__ float a1[16];
    if (tid < 32) {
        const int j = tid & 15;
        const float* wsrc = (tid < 16) ? (kw1 + j * Cx) : (ca_w1 + j * Cx);
        float acc = 0.f;
        #pragma unroll 8
        for (int c = 0; c < Cx; ++c) acc = fmaf(x_deg[b * Cx + c], wsrc[c], acc);
        acc = acc > 0.f ? acc : 0.1f * acc;               // leaky_relu 0.1
        if (tid < 16) h1[j] = acc; else a1[j] = acc;
    }
    __syncthreads();

    for (int o4 = tid; o4 < 4 * 576; o4 += 256) {
        const int g = o4 / 576;
        const int o = o4 - g * 576;
        float acc = 0.f;
        #pragma unroll
        for (int i = 0; i < 4; ++i)
            acc = fmaf(h1[g * 4 + i], kw2[(g * 576 + o) * 4 + i], acc);
        const int c = o / 9;
        const int k = o - c * 9;
        ws[WS_KERN + b * 2304 + c * 36 + k * 4 + g] = acc;
    }
    {
        const int r = tid >> 6;
        const int c = tid & 63;
        float acc = 0.f;
        #pragma unroll
        for (int i = 0; i < 4; ++i)
            acc = fmaf(a1[r * 4 + i], ca_w2[(r * Cx + c) * 4 + i], acc);
        ws[WS_ATT + b * 256 + c * 4 + r] = 1.f / (1.f + expf(-acc));
    }
}

// ---------------- main fused kernel: R10 skeleton + MFMA 1x1 ----------------
// R10 diagnosis: LDS pipe saturated; cw b128 reads (1024/thread) were 45%.
// Pass 2 now: depthwise conv as before -> routed bf16 -> 1 ds_write_b128 per
// thread per chunk into swizzled rbuf; after the loop ONE 64x64x64 GEMM per
// wave (32 mfma_16x16x32_bf16), result redistributed via padded LDS transpose.
// Spill law respected: no staging/compute interleave; chunk-loop live state
// is now SMALLER than R10 (no y[64] during staging).
__global__ __launch_bounds__(256, 2)
void da_main(const float* __restrict__ x0,
             const float* __restrict__ ws,
             const float* __restrict__ g1b,
             const float* __restrict__ g2b,
             const float* __restrict__ convb,
             float* __restrict__ out)
{
    const int b  = blockIdx.z;
    const int h0 = blockIdx.y * TH;
    const int w0 = blockIdx.x * TW;
    const int tid = threadIdx.x;
    const int tx = tid & (TW - 1);
    const int ty = tid >> 5;
    const int lane = tid & 63;
    const int wave = tid >> 6;

    // swts: pass1 = gpack [c][rg][12] (6144); pass2 = skern[0,2304)+satt[2304,2560)
    __shared__ __align__(16) float swts[6656];            // 26.0 KB
    // sxy: pass chunks sx[0,2720); GEMM transpose sy[0,4352) (4 waves x 64 x 17)
    __shared__ __align__(16) float sxy[4352];             // 17.0 KB
    // rbuf: routed bf16 [wave][64 pix][64 ch], XOR-swizzled 16B slots
    __shared__ __align__(16) unsigned int rbuf_u[8192];   // 32.0 KB
    // total 75 KB -> 2 blocks/CU

    const float* xb  = x0 + (size_t)b * Cx * HWx;
    const float* kws = ws + WS_KERN + b * 2304;
    const float* aws = ws + WS_ATT  + b * 256;
    const unsigned int* wsu = (const unsigned int*)ws;

    // --- per-thread staging offsets, computed ONCE (named ints, no array) ---
    int o0, o1, o2, o3, o4, o5, o6, o7, o8, o9, o10;
    unsigned vmask = 0u;
#define MKOFF(i, oname)                                                        \
    do {                                                                       \
        const int e   = tid + (i) * 256;                                       \
        const int cc  = e / CPLANE;                                            \
        const int rem = e - cc * CPLANE;                                       \
        const int row = rem / HALO_W;                                          \
        const int col = rem - row * HALO_W;                                    \
        const int gh  = h0 - 1 + row;                                          \
        const int gw  = w0 - 1 + col;                                          \
        oname = cc * HWx + gh * Wx + gw;                                       \
        if (e < CHUNK_ELEMS && (unsigned)gh < Hx && (unsigned)gw < Wx)         \
            vmask |= (1u << (i));                                              \
    } while (0)
    MKOFF(0, o0);  MKOFF(1, o1);  MKOFF(2, o2);  MKOFF(3, o3);
    MKOFF(4, o4);  MKOFF(5, o5);  MKOFF(6, o6);  MKOFF(7, o7);
    MKOFF(8, o8);  MKOFF(9, o9);  MKOFF(10, o10);
#undef MKOFF

    // batched staging: issue all loads, then all LDS writes (R10-proven)
#define STAGE_CHUNK(ch)                                                        \
    do {                                                                       \
        const float* src = xb + (size_t)(ch) * CCH * HWx;                      \
        float v0 = 0.f, v1 = 0.f, v2 = 0.f, v3 = 0.f, v4 = 0.f, v5 = 0.f;     \
        float v6 = 0.f, v7 = 0.f, v8 = 0.f, v9 = 0.f, v10 = 0.f;              \
        if (vmask & 1u)      v0  = src[o0];                                    \
        if (vmask & 2u)      v1  = src[o1];                                    \
        if (vmask & 4u)      v2  = src[o2];                                    \
        if (vmask & 8u)      v3  = src[o3];                                    \
        if (vmask & 16u)     v4  = src[o4];                                    \
        if (vmask & 32u)     v5  = src[o5];                                    \
        if (vmask & 64u)     v6  = src[o6];                                    \
        if (vmask & 128u)    v7  = src[o7];                                    \
        if (vmask & 256u)    v8  = src[o8];                                    \
        if (vmask & 512u)    v9  = src[o9];                                    \
        if (vmask & 1024u)   v10 = src[o10];                                   \
        sxy[tid]          = v0;   sxy[tid + 256]  = v1;                        \
        sxy[tid + 512]    = v2;   sxy[tid + 768]  = v3;                        \
        sxy[tid + 1024]   = v4;   sxy[tid + 1280] = v5;                        \
        sxy[tid + 1536]   = v6;   sxy[tid + 1792] = v7;                        \
        sxy[tid + 2048]   = v8;   sxy[tid + 2304] = v9;                        \
        if (tid < CHUNK_ELEMS - 2560) sxy[tid + 2560] = v10;                   \
    } while (0)

    // --- prologue: pass-1 guide weights, batched float4 copies ---
    {
        const float4* s4 = (const float4*)(ws + WS_GPACK);
        float4* d4 = (float4*)swts;
        const float4 g0 = s4[tid], g1 = s4[tid + 256], g2 = s4[tid + 512];
        const float4 g3 = s4[tid + 768], g4 = s4[tid + 1024], g5 = s4[tid + 1280];
        d4[tid] = g0; d4[tid + 256] = g1; d4[tid + 512] = g2;
        d4[tid + 768] = g3; d4[tid + 1024] = g4; d4[tid + 1280] = g5;
    }

    // ================= PASS 1: guide convs -> argmax (byte-identical) =================
    float ga[8];
    #pragma unroll
    for (int r = 0; r < 4; ++r) { ga[r] = g1b[r]; ga[4 + r] = g2b[r]; }

    #pragma unroll 1
    for (int ch = 0; ch < NCHUNK; ++ch) {
        __syncthreads();
        STAGE_CHUNK(ch);
        __syncthreads();

        float pg[8] = {0.f, 0.f, 0.f, 0.f, 0.f, 0.f, 0.f, 0.f};
        #pragma unroll
        for (int cc = 0; cc < CCH; ++cc) {
            const int c = ch * CCH + cc;
            float n[9];
            #pragma unroll
            for (int kh = 0; kh < 3; ++kh)
                #pragma unroll
                for (int kw = 0; kw < 3; ++kw)
                    n[kh * 3 + kw] = sxy[cc * CPLANE + (ty + kh) * HALO_W + (tx + kw)];
            const float4* gpv = (const float4*)(swts + c * 96);  // uniform b128 broadcast
            #pragma unroll
            for (int rg = 0; rg < 8; ++rg) {
                const float4 q0 = gpv[rg * 3 + 0];
                const float4 q1 = gpv[rg * 3 + 1];
                const float4 q2 = gpv[rg * 3 + 2];
                float s = 0.f;                        // k-ascending, bit-identical chain
                s = fmaf(n[0], q0.x, s); s = fmaf(n[1], q0.y, s); s = fmaf(n[2], q0.z, s);
                s = fmaf(n[3], q0.w, s); s = fmaf(n[4], q1.x, s); s = fmaf(n[5], q1.y, s);
                s = fmaf(n[6], q1.z, s); s = fmaf(n[7], q1.w, s); s = fmaf(n[8], q2.x, s);
                pg[(rg >> 1) + (rg & 1) * 4] += s;
            }
        }
        #pragma unroll
        for (int i = 0; i < 8; ++i) ga[i] += pg[i];
    }

    int r1 = 0, r2 = 0;
    {
        float m = ga[0];
        #pragma unroll
        for (int r = 1; r < 4; ++r) if (ga[r] > m) { m = ga[r]; r1 = r; }   // first-max ties
        float m2 = ga[4];
        #pragma unroll
        for (int r = 1; r < 4; ++r) if (ga[4 + r] > m2) { m2 = ga[4 + r]; r2 = r; }
    }

    // --- pass transition: stage skern+satt into LDS (batched) ---
    __syncthreads();
    {
        const float4* k4 = (const float4*)kws;
        const float4 k0 = k4[tid], k1 = k4[tid + 256];
        const float kt = kws[2048 + tid];
        const float at = aws[tid];
        float4* kd4 = (float4*)swts;                  // skern at 0
        kd4[tid] = k0; kd4[tid + 256] = k1;
        swts[2048 + tid] = kt;                        // skern tail
        swts[2304 + tid] = at;                        // satt
    }

    // ================= PASS 2: routed depthwise -> bf16 rbuf =================
    #pragma unroll 1
    for (int ch = 0; ch < NCHUNK; ++ch) {
        __syncthreads();
        STAGE_CHUNK(ch);
        __syncthreads();

        unsigned int us[4] = {0u, 0u, 0u, 0u};
        #pragma unroll
        for (int cc = 0; cc < CCH; ++cc) {
            const int c = ch * CCH + cc;
            float n[9];
            #pragma unroll
            for (int kh = 0; kh < 3; ++kh)
                #pragma unroll
                for (int kw = 0; kw < 3; ++kw)
                    n[kh * 3 + kw] = sxy[cc * CPLANE + (ty + kh) * HALO_W + (tx + kw)];

            float dw = 0.f;
            #pragma unroll
            for (int k = 0; k < 9; ++k)
                dw = fmaf(n[k], swts[c * 36 + k * 4 + r1], dw);
            const float routed = dw > 0.f ? dw : 0.1f * dw;

            us[cc >> 1] |= rne_bf16(routed) << ((cc & 1) * 16);   // static idx (unrolled)
        }
        // one swizzled b128 write: rbuf[wave][pix=lane][chunk slot ^ (pix&7)]
        {
            const int byteoff = wave * 8192 + lane * 128 + ((ch * 16) ^ ((lane & 7) << 4));
            *(u32x4*)((char*)rbuf_u + byteoff) = (u32x4){us[0], us[1], us[2], us[3]};
        }
    }
    __syncthreads();   // sx dead; rbuf complete; sy region reuse safe

    // ================= GEMM: Y[64pix][64o] = R * W  (per wave) =================
    float y[Cx];
    {
        f32x4 acc[4][4];
        #pragma unroll
        for (int mt = 0; mt < 4; ++mt)
            #pragma unroll
            for (int nt = 0; nt < 4; ++nt)
                acc[mt][nt] = (f32x4){0.f, 0.f, 0.f, 0.f};

        const bf16x8* bglob = (const bf16x8*)(wsu + WS_CWB);
        #pragma unroll
        for (int ks = 0; ks < 2; ++ks) {
            bf16x8 av[4];
            #pragma unroll
            for (int mt = 0; mt < 4; ++mt) {
                const int pix = mt * 16 + (lane & 15);
                const int byteoff = wave * 8192 + pix * 128 +
                    ((ks * 64 + ((lane >> 4) * 16)) ^ ((pix & 7) << 4));
                av[mt] = *(const bf16x8*)((const char*)rbuf_u + byteoff);
            }
            bf16x8 bv[4];
            #pragma unroll
            for (int nt = 0; nt < 4; ++nt)
                bv[nt] = bglob[(nt * 2 + ks) * 64 + lane];
            #pragma unroll
            for (int mt = 0; mt < 4; ++mt)
                #pragma unroll
                for (int nt = 0; nt < 4; ++nt)
                    acc[mt][nt] = __builtin_amdgcn_mfma_f32_16x16x32_bf16(
                        av[mt], bv[nt], acc[mt][nt], 0, 0, 0);
        }

        // redistribute: lane holds D[pix=(lane>>4)*4+q + mt*16][o=nt*16+(lane&15)]
        // -> thread-owns-pixel via padded (stride 17) per-wave LDS transpose
        #pragma unroll
        for (int nt = 0; nt < 4; ++nt) {
            #pragma unroll
            for (int mt = 0; mt < 4; ++mt)
                #pragma unroll
                for (int q = 0; q < 4; ++q)
                    sxy[wave * 1088 + (mt * 16 + (lane >> 4) * 4 + q) * 17 + (lane & 15)]
                        = acc[mt][nt][q];
            // same-wave write->read: lgkmcnt ordering by compiler
            #pragma unroll
            for (int t = 0; t < 16; ++t)
                y[nt * 16 + t] = sxy[wave * 1088 + lane * 17 + t];
        }
    }

    // --- epilogue: bias + CA branch (x center re-read) + store ---
    const int hh = h0 + ty;
    const int ww = w0 + tx;
    float* op = out + (size_t)b * Cx * HWx + hh * Wx + ww;
    const float* xp = xb + hh * Wx + ww;
    #pragma unroll
    for (int o = 0; o < Cx; ++o) {
        const float v = y[o] + convb[o] + xp[(size_t)o * HWx] * swts[2304 + o * 4 + r2];
        op[(size_t)o * HWx] = v;
    }
}

extern "C" void kernel_launch(void* const* d_in, const int* in_sizes, int n_in,
                              void* d_out, int out_size, void* d_ws, size_t ws_size,
                              hipStream_t stream) {
    const float* x0     = (const float*)d_in[0];
    const float* x_deg  = (const float*)d_in[1];
    const float* kw1    = (const float*)d_in[2];
    const float* kw2    = (const float*)d_in[3];
    const float* convw  = (const float*)d_in[4];
    const float* convb  = (const float*)d_in[5];
    const float* ca_w1  = (const float*)d_in[6];
    const float* ca_w2  = (const float*)d_in[7];
    const float* g1w    = (const float*)d_in[8];
    const float* g1b    = (const float*)d_in[9];
    const float* g2w    = (const float*)d_in[10];
    const float* g2b    = (const float*)d_in[11];
    float* outp = (float*)d_out;
    float* wsf  = (float*)d_ws;

    da_prep<<<Bx + 1, 256, 0, stream>>>(x_deg, kw1, kw2, convw, ca_w1, ca_w2,
                                        g1w, g2w, wsf);

    dim3 grid(Wx / TW, Hx / TH, Bx);   // 4 x 16 x 16 = 1024 blocks
    da_main<<<grid, 256, 0, stream>>>(x0, wsf, g1b, g2b, convb, outp);
}